// Round 3
// baseline (1461.596 us; speedup 1.0000x reference)
//
#include <hip/hip_runtime.h>
#include <hip/hip_fp16.h>
#include <math.h>
#include <stdint.h>

#define HH 512
#define WW 512
#define NIMG 24
#define CCH 3
#define TAU 0.25f
#define TVEPS 2e-4f
#define NUMEL 262144.0f
#define TS 128
#define NBLK 384

// ws layout (256 MiB):
//   byte 0     : barrier counters unsigned[64] (memset 0 each launch)
//   byte 4096  : par float2 [2][NIMG][16]   (parity = t&1)
//   byte 65536 : ptg0 edge-mirror field (uint32 half2 per px, 24*512*512)
//   byte 65536+25165824 : ptg1
// Only the 4 edge lines of each 128x128 tile are ever written/read in ptg;
// interior is never touched (stale/poisoned content harmless).

__device__ __forceinline__ float2 h2f(uint32_t v) {
    __half2 h; *reinterpret_cast<uint32_t*>(&h) = v;
    return __half22float2(h);
}
__device__ __forceinline__ uint32_t f2h2(float a, float b) {
    __half2 h = __floats2half2_rn(a, b);
    return *reinterpret_cast<uint32_t*>(&h);
}

// Device-scope grid barrier, per-epoch counter slot (no reuse -> no reset race).
// threadfence = agent-scope fence (L2 writeback / invalidate on gfx950).
__device__ __forceinline__ void gridbar(unsigned* cnt, int e, int tid) {
    __syncthreads();                       // all waves' stores complete (vmcnt drained)
    if (tid == 0) {
        __threadfence();                   // release: write back this XCD's L2
        atomicAdd(&cnt[e], 1u);
        unsigned it = 0;
        while (__hip_atomic_load(&cnt[e], __ATOMIC_ACQUIRE, __HIP_MEMORY_SCOPE_AGENT) < NBLK) {
            __builtin_amdgcn_s_sleep(4);
            if (++it > (1u << 22)) break;  // bailout: never hang the harness
        }
    }
    __syncthreads();
    __threadfence();                       // acquire (all threads): invalidate stale L1/L2
}

__global__ __launch_bounds__(512, 4) void tv_all(
    const float* __restrict__ img, const float* __restrict__ weight,
    float* __restrict__ outg,
    uint32_t* __restrict__ ptg0, uint32_t* __restrict__ ptg1,
    float2* __restrict__ par, unsigned* __restrict__ cnt)
{
    const int im = blockIdx.z, bx = blockIdx.x, by = blockIdx.y;
    const int x0 = bx * TS, y0 = by * TS;
    const int tid = threadIdx.x;
    const int tx = tid & 31, ry = tid >> 5;       // strip(4 cols) x band(8 rows)
    const int cx = x0 + 4 * tx;
    const int bid = by * 4 + bx;
    const float w = weight[im / CCH];
    const float tw = TAU / w;

    const float* imgI = img + (size_t)im * HH * WW;
    float* outI = outg + (size_t)im * HH * WW;
    uint32_t* pe0 = ptg0 + (size_t)im * HH * WW;
    uint32_t* pe1 = ptg1 + (size_t)im * HH * WW;

    __shared__ uint32_t bndP[16][128];   // band-boundary pt rows (row 7 of each band)
    __shared__ float    bndO[16][128];   // band-boundary out rows (row 0 of each band)
    __shared__ float    wsum[8][2];
    __shared__ int      sdone;

    // ---- prologue: load img f32 into out regs; pack half img; pt = 0 ----
    float out[8][4];
    uint32_t imh[8][2];
    uint32_t pt[8][4];
    #pragma unroll
    for (int i = 0; i < 8; ++i) {
        float4 v = *(const float4*)(imgI + (size_t)(y0 + 8 * ry + i) * WW + cx);
        out[i][0] = v.x; out[i][1] = v.y; out[i][2] = v.z; out[i][3] = v.w;
        imh[i][0] = f2h2(v.x, v.y); imh[i][1] = f2h2(v.z, v.w);
        pt[i][0] = 0u; pt[i][1] = 0u; pt[i][2] = 0u; pt[i][3] = 0u;
    }
    // halo img: south row (ry==15, by<3) and east col (tx==31, bx<3).
    // hs/he preset with f32 img (iteration-0 gradients use full f32, like reference).
    float hs[4] = {0, 0, 0, 0}, he[8] = {0, 0, 0, 0, 0, 0, 0, 0};
    uint32_t imhS[2] = {0, 0}, imhE4[4] = {0, 0, 0, 0};
    if (ry == 15 && by < 3) {
        float4 v = *(const float4*)(imgI + (size_t)(y0 + TS) * WW + cx);
        hs[0] = v.x; hs[1] = v.y; hs[2] = v.z; hs[3] = v.w;
        imhS[0] = f2h2(v.x, v.y); imhS[1] = f2h2(v.z, v.w);
    }
    if (tx == 31 && bx < 3) {
        float ev[8];
        #pragma unroll
        for (int i = 0; i < 8; ++i)
            ev[i] = imgI[(size_t)(y0 + 8 * ry + i) * WW + x0 + TS];
        #pragma unroll
        for (int i = 0; i < 8; ++i) he[i] = ev[i];
        imhE4[0] = f2h2(ev[0], ev[1]); imhE4[1] = f2h2(ev[2], ev[3]);
        imhE4[2] = f2h2(ev[4], ev[5]); imhE4[3] = f2h2(ev[6], ev[7]);
    }

    float Eprev = 0.f, Einit = 0.f;
    int done = 0;

    for (int t = 0; t <= 9; ++t) {
        float accd = 0.f;
        if (!done) {
            if (t >= 1) {
                const uint32_t* src = (((t - 1) & 1) == 0) ? pe0 : pe1;
                // stage pt_{t-1} band-boundary rows for div's up-neighbor
                *(uint4*)&bndP[ry][4 * tx] =
                    make_uint4(pt[7][0], pt[7][1], pt[7][2], pt[7][3]);
                __syncthreads();
                // global halo loads (pt_{t-1} edges published by neighbors)
                uint4 nh = make_uint4(0, 0, 0, 0);
                if (ry == 0 && y0 > 0)
                    nh = *(const uint4*)(src + (size_t)(y0 - 1) * WW + cx);
                uint32_t wv[8];
                if (tx == 0 && x0 > 0) {
                    #pragma unroll
                    for (int i = 0; i < 8; ++i)
                        wv[i] = src[(size_t)(y0 + 8 * ry + i) * WW + x0 - 1];
                } else {
                    #pragma unroll
                    for (int i = 0; i < 8; ++i) wv[i] = 0u;
                }
                uint4 sh = make_uint4(0, 0, 0, 0); uint32_t swc = 0u;
                if (ry == 15 && by < 3 && t < 9) {
                    sh = *(const uint4*)(src + (size_t)(y0 + TS) * WW + cx);
                    if (tx == 0 && x0 > 0) swc = src[(size_t)(y0 + TS) * WW + x0 - 1];
                }
                uint32_t eh[8], ehu = 0u;
                if (tx == 31 && bx < 3 && t < 9) {
                    #pragma unroll
                    for (int i = 0; i < 8; ++i)
                        eh[i] = src[(size_t)(y0 + 8 * ry + i) * WW + x0 + TS];
                    int yup = y0 + 8 * ry - 1;
                    ehu = (yup >= 0) ? src[(size_t)yup * WW + x0 + TS] : 0u;
                } else {
                    #pragma unroll
                    for (int i = 0; i < 8; ++i) eh[i] = 0u;
                }
                // ---- OUT phase: out_t = img_h + div(pt_{t-1}) ----
                uint4 bp = make_uint4(0, 0, 0, 0);
                if (ry > 0) bp = *(uint4*)&bndP[ry - 1][4 * tx];
                uint32_t nha[4] = {nh.x, nh.y, nh.z, nh.w};
                uint32_t bpa[4] = {bp.x, bp.y, bp.z, bp.w};
                #pragma unroll
                for (int i = 0; i < 8; ++i) {
                    uint32_t wshfl = __shfl_up(pt[i][3], 1, 64);
                    uint32_t ww = (tx > 0) ? wshfl : wv[i];   // 0 at image edge
                    #pragma unroll
                    for (int j = 0; j < 4; ++j) {
                        float2 cf = h2f(pt[i][j]);
                        float up;
                        if (i > 0)       up = h2f(pt[i - 1][j]).x;
                        else if (ry > 0) up = h2f(bpa[j]).x;
                        else             up = h2f(nha[j]).x;  // 0 when y0==0
                        float lf = (j > 0) ? h2f(pt[i][j - 1]).y : h2f(ww).y;
                        float dv = -(cf.x + cf.y) + up + lf;
                        float2 i2 = h2f(imh[i][j >> 1]);
                        float imf = (j & 1) ? i2.y : i2.x;
                        out[i][j] = imf + dv;
                        accd += dv * dv;
                    }
                }
                // redundant halo-out (south row 128 / east col 128) for grad locality
                if (t < 9) {
                    if (ry == 15 && by < 3) {
                        uint32_t sa[4] = {sh.x, sh.y, sh.z, sh.w};
                        uint32_t sshfl = __shfl_up(sh.w, 1, 64);
                        uint32_t sww = (tx > 0) ? sshfl : swc;
                        #pragma unroll
                        for (int j = 0; j < 4; ++j) {
                            float2 cf = h2f(sa[j]);
                            float up = h2f(pt[7][j]).x;
                            float lf = (j > 0) ? h2f(sa[j - 1]).y : h2f(sww).y;
                            float2 i2 = h2f(imhS[j >> 1]);
                            hs[j] = ((j & 1) ? i2.y : i2.x) + (-(cf.x + cf.y) + up + lf);
                        }
                    }
                    if (tx == 31 && bx < 3) {
                        uint32_t prev = ehu;
                        #pragma unroll
                        for (int i = 0; i < 8; ++i) {
                            float2 cf = h2f(eh[i]);
                            float up = h2f(prev).x;
                            float lf = h2f(pt[i][3]).y;
                            float2 i2 = h2f(imhE4[i >> 1]);
                            he[i] = ((i & 1) ? i2.y : i2.x) + (-(cf.x + cf.y) + up + lf);
                            prev = eh[i];
                        }
                    }
                }
            } // t>=1

            if (t <= 8) {
                // ---- PT phase: pt_t from grad(out_t) ----
                __syncthreads();
                *(float4*)&bndO[ry][4 * tx] =
                    make_float4(out[0][0], out[0][1], out[0][2], out[0][3]);
                __syncthreads();
                float4 b4 = make_float4(0, 0, 0, 0);
                if (ry < 15) b4 = *(float4*)&bndO[ry + 1][4 * tx];
                float bno[4] = {b4.x, b4.y, b4.z, b4.w};
                float accn = 0.f;
                #pragma unroll
                for (int i = 0; i < 8; ++i) {
                    float eshfl = __shfl_down(out[i][0], 1, 64);
                    float ev = (tx < 31) ? eshfl : he[i];
                    int y = y0 + 8 * ry + i;
                    #pragma unroll
                    for (int j = 0; j < 4; ++j) {
                        float o = out[i][j];
                        float bel = (i < 7) ? out[i + 1][j] : ((ry < 15) ? bno[j] : hs[j]);
                        float g0 = (y < HH - 1) ? bel - o : 0.f;
                        float rn = (j < 3) ? out[i][j + 1] : ev;
                        float g1 = (cx + j < WW - 1) ? rn - o : 0.f;
                        float ss2 = g0 * g0 + g1 * g1;
                        float nrm = (ss2 > 0.f) ? sqrtf(ss2) : 0.f;
                        accn += nrm;
                        float inv = __builtin_amdgcn_rcpf(1.f + tw * nrm);
                        float2 cf = h2f(pt[i][j]);
                        pt[i][j] = f2h2((cf.x - TAU * g0) * inv, (cf.y - TAU * g1) * inv);
                    }
                }
                // publish new pt edges (parity t&1)
                uint32_t* dst = ((t & 1) == 0) ? pe0 : pe1;
                if (ry == 0)
                    *(uint4*)(dst + (size_t)y0 * WW + cx) =
                        make_uint4(pt[0][0], pt[0][1], pt[0][2], pt[0][3]);
                if (ry == 15)
                    *(uint4*)(dst + (size_t)(y0 + TS - 1) * WW + cx) =
                        make_uint4(pt[7][0], pt[7][1], pt[7][2], pt[7][3]);
                if (tx == 0) {
                    #pragma unroll
                    for (int i = 0; i < 8; ++i)
                        dst[(size_t)(y0 + 8 * ry + i) * WW + x0] = pt[i][0];
                }
                if (tx == 31) {
                    #pragma unroll
                    for (int i = 0; i < 8; ++i)
                        dst[(size_t)(y0 + 8 * ry + i) * WW + x0 + TS - 1] = pt[i][3];
                }
                // block partial (deterministic fixed-order reduce)
                float d = accd, n = accn;
                for (int off = 32; off > 0; off >>= 1) {
                    d += __shfl_down(d, off, 64);
                    n += __shfl_down(n, off, 64);
                }
                if ((tid & 63) == 0) { wsum[tid >> 6][0] = d; wsum[tid >> 6][1] = n; }
                __syncthreads();
                if (tid == 0) {
                    float td = 0.f, tn = 0.f;
                    #pragma unroll
                    for (int k = 0; k < 8; ++k) { td += wsum[k][0]; tn += wsum[k][1]; }
                    par[((size_t)(t & 1) * NIMG + im) * 16 + bid] = make_float2(td, tn);
                }
            }
        } // !done

        if (t <= 8) {
            gridbar(cnt, t, tid);
            if (!done) {
                float dd = 0.f, nn = 0.f;
                if (tid < 16) {
                    float2 p = par[((size_t)(t & 1) * NIMG + im) * 16 + tid];
                    dd = p.x; nn = p.y;
                    for (int off = 8; off > 0; off >>= 1) {
                        dd += __shfl_xor(dd, off, 16);
                        nn += __shfl_xor(nn, off, 16);
                    }
                }
                if (tid == 0) {
                    float Et = (dd + w * nn) / NUMEL;   // /2^18: exact
                    int dn = 0;
                    if (t == 0) { Einit = Et; Eprev = Et; }
                    else if (fabsf(Eprev - Et) < TVEPS * Einit) dn = 1;
                    else Eprev = Et;
                    sdone = dn;
                }
                __syncthreads();
                done = sdone;   // frozen from next iteration on (out regs = out_t)
            }
        }
    }

    // epilogue: out regs hold out_k (k = first converged iter, else 9)
    #pragma unroll
    for (int i = 0; i < 8; ++i) {
        *(float4*)(outI + (size_t)(y0 + 8 * ry + i) * WW + cx) =
            make_float4(out[i][0], out[i][1], out[i][2], out[i][3]);
    }
}

extern "C" void kernel_launch(void* const* d_in, const int* in_sizes, int n_in,
                              void* d_out, int out_size, void* d_ws, size_t ws_size,
                              hipStream_t stream)
{
    const float* img = (const float*)d_in[0];
    const float* weight = (const float*)d_in[1];
    float* out = (float*)d_out;
    unsigned* cnt = (unsigned*)d_ws;
    float2* par = (float2*)((char*)d_ws + 4096);
    uint32_t* ptg0 = (uint32_t*)((char*)d_ws + 65536);
    uint32_t* ptg1 = (uint32_t*)((char*)d_ws + 65536 + 25165824);

    hipMemsetAsync(cnt, 0, 1024, stream);
    tv_all<<<dim3(4, 4, NIMG), dim3(512), 0, stream>>>(
        img, weight, out, ptg0, ptg1, par, cnt);
}

// Round 4
// 232.746 us; speedup vs baseline: 6.2798x; 6.2798x over previous
//
#include <hip/hip_runtime.h>
#include <hip/hip_fp16.h>
#include <math.h>
#include <stdint.h>

#define HH 512
#define WW 512
#define NIMG 24
#define CCH 3
#define TAU 0.25f
#define TVEPS 2e-4f
#define NUMEL 262144.0f
#define NITER 10

// ws layout (256 MiB):
//   byte 0     : sc — 2 slots x 96 floats, slot s at sc+96*s:
//                [0..23]=E_prev, [24..47]=E_init, int[48..71]=done, int[72..95]=last_k
//                slot (it&1) holds state S_{it-1} after kernel `it` runs.
//   byte 4096  : pd [2][NIMG][64]  (slot = it&1)
//   byte 16384 : pn [2][NIMG][64]
//   byte 32768 : imgh (__half, 24*512*512)
//   byte 12615680 : ptA (uint32 packed half2)
//   byte 37781504 : ptB

__device__ __forceinline__ float2 h2f(uint32_t v) {
    __half2 h; *reinterpret_cast<uint32_t*>(&h) = v;
    return __half22float2(h);
}
__device__ __forceinline__ uint32_t f2h2(float a, float b) {
    __half2 h = __floats2half2_rn(a, b);
    return *reinterpret_cast<uint32_t*>(&h);
}
__device__ __forceinline__ void h4_to_f(uint2 hv, float* f) {
    float2 a = h2f(hv.x), b = h2f(hv.y);
    f[0] = a.x; f[1] = a.y; f[2] = b.x; f[3] = b.y;
}

__device__ __forceinline__ void block_reduce_store(float v0, float v1,
                                                   float* p0, float* p1, int tid) {
    for (int off = 32; off > 0; off >>= 1) {
        v0 += __shfl_down(v0, off, 64);
        v1 += __shfl_down(v1, off, 64);
    }
    __shared__ float sr[2][4];
    int wave = tid >> 6, lane = tid & 63;
    if (lane == 0) { sr[0][wave] = v0; sr[1][wave] = v1; }
    __syncthreads();
    if (tid == 0) {
        *p0 = (sr[0][0] + sr[0][1]) + (sr[0][2] + sr[0][3]);
        *p1 = (sr[1][0] + sr[1][1]) + (sr[1][2] + sr[1][3]);
    }
}

__device__ __forceinline__ void block_reduce_store1(float v, float* p, int tid) {
    for (int off = 32; off > 0; off >>= 1) v += __shfl_down(v, off, 64);
    __shared__ float sr[4];
    if ((tid & 63) == 0) sr[tid >> 6] = v;
    __syncthreads();
    if (tid == 0) *p = (sr[0] + sr[1]) + (sr[2] + sr[3]);
}

// Iteration 0: out = img. 4px-wide strips, all global I/O 16B. (round-1 verified)
__global__ __launch_bounds__(256, 4) void tv_step0(
    const float* __restrict__ img, const float* __restrict__ weight,
    __half* __restrict__ imgh, uint32_t* __restrict__ ptout,
    float* __restrict__ pn)
{
    const int im = blockIdx.z;
    const int bid = blockIdx.y * 8 + blockIdx.x;
    const float w = weight[im / CCH];
    const int x0 = blockIdx.x * 64, y0 = blockIdx.y * 64;
    const float* imgI = img + (size_t)im * HH * WW;
    __half* hI = imgh + (size_t)im * HH * WW;
    uint32_t* pI = ptout + (size_t)im * HH * WW;
    __shared__ float s[65][68];
    const int tid = threadIdx.x;
    const int tx = tid & 15, ry = tid >> 4;
    const int gx = x0 + 4 * tx;

    float o[4][4];
    #pragma unroll
    for (int i = 0; i < 4; ++i) {
        int ey = ry + 16 * i, gy = y0 + ey;
        float4 v = *(const float4*)(imgI + (size_t)gy * WW + gx);
        o[i][0] = v.x; o[i][1] = v.y; o[i][2] = v.z; o[i][3] = v.w;
        *(float4*)&s[ey][4 * tx] = v;
    }
    if (tx == 15 && x0 + 64 < WW) {
        #pragma unroll
        for (int i = 0; i < 4; ++i) {
            int ey = ry + 16 * i, gy = y0 + ey;
            s[ey][64] = imgI[(size_t)gy * WW + x0 + 64];
        }
    }
    if (ry == 0 && y0 + 64 < HH) {
        *(float4*)&s[64][4 * tx] = *(const float4*)(imgI + (size_t)(y0 + 64) * WW + gx);
    }
    __syncthreads();

    float accn = 0.f;
    const float tw = TAU / w;
    #pragma unroll
    for (int i = 0; i < 4; ++i) {
        int ey = ry + 16 * i, gy = y0 + ey;
        float4 dn = *(float4*)&s[ey + 1][4 * tx];
        float rt_sh = __shfl_down(o[i][0], 1, 64);
        float rt = (tx == 15) ? s[ey][64] : rt_sh;
        float dnv[4] = {dn.x, dn.y, dn.z, dn.w};
        uint32_t pv[4];
        #pragma unroll
        for (int j = 0; j < 4; ++j) {
            float ov = o[i][j];
            float g0 = (gy < HH - 1) ? dnv[j] - ov : 0.f;
            float rn = (j < 3) ? o[i][j + 1] : rt;
            float g1 = (gx + j < WW - 1) ? rn - ov : 0.f;
            float ss2 = g0 * g0 + g1 * g1;
            float nrm = (ss2 > 0.f) ? sqrtf(ss2) : 0.f;
            accn += nrm;
            float inv = __builtin_amdgcn_rcpf(1.f + tw * nrm);
            pv[j] = f2h2(-TAU * g0 * inv, -TAU * g1 * inv);
        }
        size_t off = (size_t)gy * WW + gx;
        *(uint4*)(pI + off) = make_uint4(pv[0], pv[1], pv[2], pv[3]);
        *(uint2*)(hI + off) = make_uint2(f2h2(o[i][0], o[i][1]), f2h2(o[i][2], o[i][3]));
    }
    block_reduce_store1(accn, &pn[im * 64 + bid], tid);
}

// Iterations 1..8 — register-tile version. Each thread owns 4 contiguous rows x 4 cols.
// Band-boundary exchange via 4KB LDS; column neighbors via shuffles; block halos from global.
__global__ __launch_bounds__(256, 4) void tv_stepN(
    int it,
    const __half* __restrict__ imgh, const float* __restrict__ weight,
    const uint32_t* __restrict__ pt_in, uint32_t* __restrict__ pt_out,
    float* __restrict__ sc, float* __restrict__ pd, float* __restrict__ pn)
{
    const int im = blockIdx.z;
    const int bid = blockIdx.y * 8 + blockIdx.x;
    const int tid = threadIdx.x;
    const float w = weight[im / CCH];

    // --- replay head: derive S_{it-1} (identical to round-1) ---
    __shared__ int sh_done;
    {
        const int slot = (it - 1) & 1;
        if (tid < 64) {
            float d = 0.f, n = pn[(slot * NIMG + im) * 64 + tid];
            if (it > 1) d = pd[(slot * NIMG + im) * 64 + tid];
            for (int off = 32; off > 0; off >>= 1) {
                d += __shfl_down(d, off, 64);
                n += __shfl_down(n, off, 64);
            }
            if (tid == 0) {
                float Eprev, Einit; int done, lastk;
                if (it == 1) {
                    float E0 = w * n / NUMEL;
                    Eprev = E0; Einit = E0; done = 0; lastk = 0;
                } else {
                    const float* sIn = sc + slot * 96;
                    Eprev = sIn[im]; Einit = sIn[24 + im];
                    done = ((const int*)sIn)[48 + im];
                    lastk = ((const int*)sIn)[72 + im];
                    if (!done) {
                        float Et = (d + w * n) / NUMEL;
                        if (fabsf(Eprev - Et) < TVEPS * Einit) { done = 1; lastk = it - 1; }
                        Eprev = Et;
                    }
                }
                if (bid == 0) {
                    float* sOut = sc + (it & 1) * 96;
                    sOut[im] = Eprev; sOut[24 + im] = Einit;
                    ((int*)sOut)[48 + im] = done;
                    ((int*)sOut)[72 + im] = lastk;
                }
                sh_done = done;
            }
        }
    }
    __syncthreads();
    if (sh_done) return;

    const int x0 = blockIdx.x * 64, y0 = blockIdx.y * 64;
    const __half* hI = imgh + (size_t)im * HH * WW;
    const uint32_t* pinI = pt_in + (size_t)im * HH * WW;
    uint32_t* poutI = pt_out + (size_t)im * HH * WW;
    const int tx = tid & 15, ty = tid >> 4;
    const int gx = x0 + 4 * tx;
    const int gy0 = y0 + 4 * ty;
    const float tw = TAU / w;

    __shared__ uint4  XP[16][16];   // pt row 3 of each band
    __shared__ float4 XO[16][16];   // out row 0 of each band

    // ---- loads: own 4 rows of pt + imgh ----
    uint4 c[4]; uint2 ih[4];
    #pragma unroll
    for (int i = 0; i < 4; ++i) {
        size_t off = (size_t)(gy0 + i) * WW + gx;
        c[i] = *(const uint4*)(pinI + off);
        ih[i] = *(const uint2*)(hI + off);
    }
    XP[ty][tx] = c[3];

    // halos (edge threads only)
    uint32_t lf[4] = {0u, 0u, 0u, 0u};
    if (tx == 0 && x0 > 0) {
        #pragma unroll
        for (int i = 0; i < 4; ++i) lf[i] = pinI[(size_t)(gy0 + i) * WW + x0 - 1];
    }
    uint4 upg = make_uint4(0u, 0u, 0u, 0u);
    if (ty == 0 && y0 > 0) upg = *(const uint4*)(pinI + (size_t)(y0 - 1) * WW + gx);

    uint32_t ep[5] = {0u, 0u, 0u, 0u, 0u};
    float ihE[4] = {0.f, 0.f, 0.f, 0.f};
    const bool hasE = (tx == 15) && (x0 + 64 < WW);
    if (hasE) {
        const int xe = x0 + 64;
        ep[0] = (gy0 > 0) ? pinI[(size_t)(gy0 - 1) * WW + xe] : 0u;
        #pragma unroll
        for (int i = 0; i < 4; ++i) {
            ep[i + 1] = pinI[(size_t)(gy0 + i) * WW + xe];
            ihE[i] = __half2float(hI[(size_t)(gy0 + i) * WW + xe]);
        }
    }
    uint4 sp = make_uint4(0u, 0u, 0u, 0u); uint2 ihS = make_uint2(0u, 0u);
    uint32_t spl = 0u;
    const bool hasS = (ty == 15) && (y0 + 64 < HH);
    if (hasS) {
        size_t off = (size_t)(y0 + 64) * WW + gx;
        sp = *(const uint4*)(pinI + off);
        ihS = *(const uint2*)(hI + off);
        if (tx == 0 && x0 > 0) spl = pinI[(size_t)(y0 + 64) * WW + x0 - 1];
    }
    __syncthreads();

    // ---- OUT phase: o = img_h + div(pt_in) ----
    uint4 up4 = (ty > 0) ? XP[ty - 1][tx] : upg;
    float o[4][4];
    float accd = 0.f;
    {
        uint32_t ca[4][4] = {{c[0].x, c[0].y, c[0].z, c[0].w},
                             {c[1].x, c[1].y, c[1].z, c[1].w},
                             {c[2].x, c[2].y, c[2].z, c[2].w},
                             {c[3].x, c[3].y, c[3].z, c[3].w}};
        uint32_t ua[4] = {up4.x, up4.y, up4.z, up4.w};
        #pragma unroll
        for (int i = 0; i < 4; ++i) {
            uint32_t lsh = __shfl_up(ca[i][3], 1, 64);
            uint32_t lw = (tx > 0) ? lsh : lf[i];
            float imv[4]; h4_to_f(ih[i], imv);
            #pragma unroll
            for (int j = 0; j < 4; ++j) {
                float2 cf = h2f(ca[i][j]);
                float up = (i > 0) ? h2f(ca[i - 1][j]).x : h2f(ua[j]).x;
                float le = (j > 0) ? h2f(ca[i][j - 1]).y : h2f(lw).y;
                float dv = -(cf.x + cf.y) + up + le;
                o[i][j] = imv[j] + dv;
                accd += dv * dv;
            }
        }
    }

    // halo-out: east col (x0+64), own 4 rows
    float he[4] = {0.f, 0.f, 0.f, 0.f};
    if (hasE) {
        uint32_t prev = ep[0];
        #pragma unroll
        for (int i = 0; i < 4; ++i) {
            float2 cf = h2f(ep[i + 1]);
            float up = h2f(prev).x;
            float le = h2f(c[i].w).y;
            he[i] = ihE[i] + (-(cf.x + cf.y) + up + le);
            prev = ep[i + 1];
        }
    }
    // halo-out: south row (y0+64)
    float hs[4] = {0.f, 0.f, 0.f, 0.f};
    if (hasS) {
        uint32_t ssh = __shfl_up(sp.w, 1, 64);
        uint32_t sl = (tx > 0) ? ssh : spl;
        uint32_t sa[4] = {sp.x, sp.y, sp.z, sp.w};
        float smv[4]; h4_to_f(ihS, smv);
        #pragma unroll
        for (int j = 0; j < 4; ++j) {
            float2 cf = h2f(sa[j]);
            float up = h2f(c[3].x * 0u + (&c[3].x)[j]).x;  // c[3] component j
            float le = (j > 0) ? h2f(sa[j - 1]).y : h2f(sl).y;
            hs[j] = smv[j] + (-(cf.x + cf.y) + up + le);
        }
    }

    XO[ty][tx] = make_float4(o[0][0], o[0][1], o[0][2], o[0][3]);
    __syncthreads();

    // ---- PT phase: gradients of out, pt update ----
    float bel4[4];
    if (ty < 15) {
        float4 t = XO[ty + 1][tx];
        bel4[0] = t.x; bel4[1] = t.y; bel4[2] = t.z; bel4[3] = t.w;
    } else {
        bel4[0] = hs[0]; bel4[1] = hs[1]; bel4[2] = hs[2]; bel4[3] = hs[3];
    }
    float accn = 0.f;
    #pragma unroll
    for (int i = 0; i < 4; ++i) {
        int gy = gy0 + i;
        float esh = __shfl_down(o[i][0], 1, 64);
        float rt = (tx < 15) ? esh : he[i];
        uint32_t ca[4] = {c[i].x, c[i].y, c[i].z, c[i].w};
        uint32_t pv[4];
        #pragma unroll
        for (int j = 0; j < 4; ++j) {
            float ov = o[i][j];
            float below = (i < 3) ? o[i + 1][j] : bel4[j];
            float g0 = (gy < HH - 1) ? below - ov : 0.f;
            float rn = (j < 3) ? o[i][j + 1] : rt;
            float g1 = (gx + j < WW - 1) ? rn - ov : 0.f;
            float ss2 = g0 * g0 + g1 * g1;
            float nrm = (ss2 > 0.f) ? sqrtf(ss2) : 0.f;
            accn += nrm;
            float inv = __builtin_amdgcn_rcpf(1.f + tw * nrm);
            float2 cf = h2f(ca[j]);
            pv[j] = f2h2((cf.x - TAU * g0) * inv, (cf.y - TAU * g1) * inv);
        }
        *(uint4*)(poutI + (size_t)gy * WW + gx) = make_uint4(pv[0], pv[1], pv[2], pv[3]);
    }

    block_reduce_store(accd, accn,
                       &pd[((it & 1) * NIMG + im) * 64 + bid],
                       &pn[((it & 1) * NIMG + im) * 64 + bid], tid);
}

// Epilogue: out = img(fp32) + div(pt of last executed step's input). (round-1 verified)
__global__ __launch_bounds__(256, 4) void tv_out(
    const float* __restrict__ img, float* __restrict__ out,
    const uint32_t* __restrict__ ptA, const uint32_t* __restrict__ ptB,
    const float* __restrict__ weight, const float* __restrict__ sc,
    const float* __restrict__ pd, const float* __restrict__ pn)
{
    const int im = blockIdx.z;
    const int tid = threadIdx.x;
    const float w = weight[im / CCH];
    __shared__ int2 shk;
    if (tid < 64) {
        const float* sIn = sc;  // slot 0 holds S_7 after it=8
        int done = ((const int*)sIn)[48 + im];
        int lastk = ((const int*)sIn)[72 + im];
        if (!done) {
            float d = pd[im * 64 + tid];   // slot 0 = it 8's partials
            float n = pn[im * 64 + tid];
            for (int off = 32; off > 0; off >>= 1) {
                d += __shfl_down(d, off, 64);
                n += __shfl_down(n, off, 64);
            }
            if (tid == 0) {
                float Et = (d + w * n) / NUMEL;
                if (fabsf(sIn[im] - Et) < TVEPS * sIn[24 + im]) { done = 1; lastk = 8; }
            }
        }
        if (tid == 0) { shk.x = done; shk.y = lastk; }
    }
    __syncthreads();
    int k = shk.x ? shk.y : (NITER - 1);
    const uint32_t* p = ((((k - 1) & 1) == 0) ? ptA : ptB) + (size_t)im * HH * WW;
    const float* imgI = img + (size_t)im * HH * WW;
    float* outI = out + (size_t)im * HH * WW;
    const int x0 = blockIdx.x * 64, y0 = blockIdx.y * 64;
    const int tx = tid & 15, ry = tid >> 4;
    const int gx = x0 + 4 * tx;
    #pragma unroll
    for (int i = 0; i < 4; ++i) {
        int gy = y0 + ry + 16 * i;
        size_t off = (size_t)gy * WW + gx;
        uint4 cv = *(const uint4*)(p + off);
        uint4 uv = make_uint4(0u, 0u, 0u, 0u);
        if (gy > 0) uv = *(const uint4*)(p + off - WW);
        uint32_t lfv = (gx > 0) ? p[off - 1] : 0u;
        float4 iv = *(const float4*)(imgI + off);
        uint32_t cc[4] = {cv.x, cv.y, cv.z, cv.w};
        uint32_t uu[4] = {uv.x, uv.y, uv.z, uv.w};
        uint32_t lt[4] = {lfv, cv.x, cv.y, cv.z};
        float ivv[4] = {iv.x, iv.y, iv.z, iv.w};
        float r[4];
        #pragma unroll
        for (int j = 0; j < 4; ++j) {
            float2 cf = h2f(cc[j]);
            r[j] = ivv[j] + (-(cf.x + cf.y) + h2f(uu[j]).x + h2f(lt[j]).y);
        }
        *(float4*)(outI + off) = make_float4(r[0], r[1], r[2], r[3]);
    }
}

extern "C" void kernel_launch(void* const* d_in, const int* in_sizes, int n_in,
                              void* d_out, int out_size, void* d_ws, size_t ws_size,
                              hipStream_t stream)
{
    const float* img = (const float*)d_in[0];
    const float* weight = (const float*)d_in[1];
    float* out = (float*)d_out;
    float* sc = (float*)d_ws;
    float* pd = (float*)((char*)d_ws + 4096);
    float* pn = (float*)((char*)d_ws + 16384);
    __half* imgh = (__half*)((char*)d_ws + 32768);
    uint32_t* ptA = (uint32_t*)((char*)d_ws + 12615680);
    uint32_t* ptB = (uint32_t*)((char*)d_ws + 37781504);

    dim3 grid(8, 8, NIMG);
    dim3 block(256);

    tv_step0<<<grid, block, 0, stream>>>(img, weight, imgh, ptA, pn);
    for (int it = 1; it <= 8; ++it) {
        uint32_t* pin  = (((it - 1) & 1) == 0) ? ptA : ptB;
        uint32_t* pout = ((it & 1) == 0) ? ptA : ptB;
        tv_stepN<<<grid, block, 0, stream>>>(it, imgh, weight, pin, pout, sc, pd, pn);
    }
    tv_out<<<grid, block, 0, stream>>>(img, out, ptA, ptB, weight, sc, pd, pn);
}